// Round 5
// baseline (288.615 us; speedup 1.0000x reference)
//
#include <hip/hip_runtime.h>
#include <hip/hip_cooperative_groups.h>

namespace cg = cooperative_groups;

// Problem: B=4, N=1024, H=64.
// d_out: [0..262143] updated (b,i,d) fp32 ; [262144..4456447] attn (b,i,j) fp32
#define ATTN_OFF 262144

// ws float-slot offsets (1 slot = 4B):
#define WS_HIP  0          // hiP h2v-packed [b][32 hp][1024 i]        131072 slots
#define WS_HJP  131072     // hjP same                                  131072
#define WS_L16  262144     // logits fp16 [b][1024][1024]              2097152
#define WS_SMAX 2359296    // smax [16 chunk][4096 row] fp32             65536
#define WS_SSUM 2424832    // ssum [16][4096] fp32                       65536
#define WS_PART 2490368    // part [16 ks][4096 row][64 d] fp32        4194304

typedef float4 f4;
typedef _Float16 h2v __attribute__((ext_vector_type(2)));

union F4H { f4 f; h2v h[4]; };
union F2H { float2 f; h2v h[2]; };

__device__ __forceinline__ f4 ld4(const float* p) { return *reinterpret_cast<const f4*>(p); }
__device__ __forceinline__ void st4(float* p, f4 v) { *reinterpret_cast<f4*>(p) = v; }
__device__ __forceinline__ float fdot2f(h2v a, h2v b, float c) {
    return __builtin_amdgcn_fdot2(a, b, c, false);   // v_dot2_f32_f16
}
__device__ __forceinline__ h2v pack2(float a, float b) {
    h2v r; r.x = (_Float16)a; r.y = (_Float16)b; return r;
}

#define PS 132   // kd s_p row stride in h2v (528 B)

// One persistent cooperative kernel; phases separated by grid.sync().
// LDS overlay: max(phaseA 34816, phaseB 24704, phaseD 26112) = 34816 B.
__global__ __launch_bounds__(256, 2)
void fused(const float* __restrict__ x, const float* __restrict__ W1,
           const float* __restrict__ b1, const float* __restrict__ W2,
           h2v* __restrict__ hiP, h2v* __restrict__ hjP,
           _Float16* __restrict__ l16, float* __restrict__ smax,
           float* __restrict__ ssum, float* __restrict__ part,
           float* __restrict__ attn, float* __restrict__ out) {
    cg::grid_group grid = cg::this_grid();
    __shared__ __align__(16) char smem[34816];
    const int t   = threadIdx.x;
    const int bid = blockIdx.x;

    // ======== Phase A: hi' = x@W1a^T + b1 ; hj = x@W1b^T (fp16 h-pair packed) ========
    if (bid < 128) {
        float* xT  = (float*)smem;        // [d][i] pad 68
        float* w1T = xT + 64 * 68;        // [d][c]
        const int i0 = (bid & 15) * 64;
        const int b  = (bid >> 4) & 3;
        const int z  = bid >> 6;
        const int lo = t & 15;
        const int dq = t >> 4;
#pragma unroll
        for (int p = 0; p < 4; ++p) {
            const int il = p * 16 + lo;
            f4 v = ld4(&x[(size_t)(b * 1024 + i0 + il) * 64 + dq * 4]);
            xT[(dq * 4 + 0) * 68 + il] = v.x;
            xT[(dq * 4 + 1) * 68 + il] = v.y;
            xT[(dq * 4 + 2) * 68 + il] = v.z;
            xT[(dq * 4 + 3) * 68 + il] = v.w;
            f4 w = ld4(&W1[(size_t)il * 128 + z * 64 + dq * 4]);
            w1T[(dq * 4 + 0) * 68 + il] = w.x;
            w1T[(dq * 4 + 1) * 68 + il] = w.y;
            w1T[(dq * 4 + 2) * 68 + il] = w.z;
            w1T[(dq * 4 + 3) * 68 + il] = w.w;
        }
        __syncthreads();
        const int tx = t & 15;   // channel quad
        const int ty = t >> 4;   // i quad
        float acc[4][4];
        if (z == 0) {
            f4 bv = ld4(&b1[tx * 4]);
            float ba[4] = {bv.x, bv.y, bv.z, bv.w};
#pragma unroll
            for (int ii = 0; ii < 4; ++ii)
#pragma unroll
                for (int cc = 0; cc < 4; ++cc) acc[ii][cc] = ba[cc];
        } else {
#pragma unroll
            for (int ii = 0; ii < 4; ++ii)
#pragma unroll
                for (int cc = 0; cc < 4; ++cc) acc[ii][cc] = 0.f;
        }
#pragma unroll 8
        for (int d = 0; d < 64; ++d) {
            f4 xv = ld4(&xT[d * 68 + ty * 4]);
            f4 wv = ld4(&w1T[d * 68 + tx * 4]);
            float xa[4] = {xv.x, xv.y, xv.z, xv.w};
            float wa[4] = {wv.x, wv.y, wv.z, wv.w};
#pragma unroll
            for (int ii = 0; ii < 4; ++ii)
#pragma unroll
                for (int cc = 0; cc < 4; ++cc)
                    acc[ii][cc] = fmaf(xa[ii], wa[cc], acc[ii][cc]);
        }
        h2v* outp = z ? hjP : hiP;
#pragma unroll
        for (int p = 0; p < 2; ++p) {
            F4H u;
#pragma unroll
            for (int ii = 0; ii < 4; ++ii)
                u.h[ii] = pack2(acc[ii][p * 2 + 0], acc[ii][p * 2 + 1]);
            st4((float*)&outp[(size_t)(b * 32 + tx * 2 + p) * 1024 + i0 + ty * 4], u.f);
        }
    }
    grid.sync();

    // ======== Phase B: logits (fp16) + per-chunk softmax stats ========
    {
        h2v* s_hi = (h2v*)smem;           // [hp][i] 32x128
        h2v* s_hj = s_hi + 32 * 128;      // [hp][j] 32x64
        h2v* s_w2 = s_hj + 32 * 64;       // 32
        const int jT = bid & 15;
        const int iT = (bid >> 4) & 7;
        const int b  = bid >> 7;
#pragma unroll
        for (int p = 0; p < 4; ++p) {
            const int idx = p * 256 + t;
            const int hp  = idx >> 5;
            const int c4  = (idx & 31) * 4;
            st4((float*)&s_hi[hp * 128 + c4],
                ld4((const float*)&hiP[(size_t)(b * 32 + hp) * 1024 + iT * 128 + c4]));
        }
#pragma unroll
        for (int p = 0; p < 2; ++p) {
            const int idx = p * 256 + t;
            const int hp  = idx >> 4;
            const int c4  = (idx & 15) * 4;
            st4((float*)&s_hj[hp * 64 + c4],
                ld4((const float*)&hjP[(size_t)(b * 32 + hp) * 1024 + jT * 64 + c4]));
        }
        if (t < 16) {
            f4 w = ld4(&W2[t * 4]);
            s_w2[t * 2]     = pack2(w.x, w.y);
            s_w2[t * 2 + 1] = pack2(w.z, w.w);
        }
        __syncthreads();
        const int tx = t & 15;  // j quad
        const int ty = t >> 4;  // i oct
        float acc[8][4];
#pragma unroll
        for (int ii = 0; ii < 8; ++ii)
#pragma unroll
            for (int jj = 0; jj < 4; ++jj) acc[ii][jj] = 0.f;
        const h2v z2 = (h2v)0;
#pragma unroll 4
        for (int hp = 0; hp < 32; ++hp) {
            F4H a0, a1, bb;
            a0.f = ld4((const float*)&s_hi[hp * 128 + ty * 8]);
            a1.f = ld4((const float*)&s_hi[hp * 128 + ty * 8 + 4]);
            bb.f = ld4((const float*)&s_hj[hp * 64 + tx * 4]);
            const h2v w2p = s_w2[hp];
#pragma unroll
            for (int ii = 0; ii < 8; ++ii) {
                const h2v av = (ii < 4) ? a0.h[ii] : a1.h[ii - 4];
#pragma unroll
                for (int jj = 0; jj < 4; ++jj) {
                    h2v r = __builtin_elementwise_max(av + bb.h[jj], z2);
                    acc[ii][jj] = fdot2f(r, w2p, acc[ii][jj]);
                }
            }
        }
#pragma unroll
        for (int ii = 0; ii < 8; ++ii) {
            const int row = b * 1024 + iT * 128 + ty * 8 + ii;
            F2H uo;
            uo.h[0] = pack2(acc[ii][0], acc[ii][1]);
            uo.h[1] = pack2(acc[ii][2], acc[ii][3]);
            *reinterpret_cast<float2*>(&l16[(size_t)row * 1024 + jT * 64 + tx * 4]) = uo.f;
            float m = fmaxf(fmaxf(acc[ii][0], acc[ii][1]), fmaxf(acc[ii][2], acc[ii][3]));
#pragma unroll
            for (int d = 1; d < 16; d <<= 1) m = fmaxf(m, __shfl_xor(m, d));
            float s = __expf(acc[ii][0] - m) + __expf(acc[ii][1] - m) +
                      __expf(acc[ii][2] - m) + __expf(acc[ii][3] - m);
#pragma unroll
            for (int d = 1; d < 16; d <<= 1) s += __shfl_xor(s, d);
            if (tx == 0) {
                smax[jT * 4096 + row] = m;
                ssum[jT * 4096 + row] = s;
            }
        }
    }
    grid.sync();

    // ======== Phase D: stats-merge + normalize + attn write + AV partials ========
    {
        h2v*   s_p  = (h2v*)smem;         // [jp][i] 32 x PS
        h2v*   s_x  = s_p + 32 * PS;      // [jp][d] 32 x 64
        float* s_m  = (float*)(s_x + 32 * 64);
        float* s_il = s_m + 128;
        const int ks = bid & 15;
        const int iT = (bid >> 4) & 7;
        const int b  = bid >> 7;
        const int j0 = ks * 64;
        const int gr = b * 1024 + iT * 128;
        if (t < 128) {
            float mv[16], sv[16];
#pragma unroll
            for (int c = 0; c < 16; ++c) {
                mv[c] = smax[c * 4096 + gr + t];
                sv[c] = ssum[c * 4096 + gr + t];
            }
            float M = mv[0];
#pragma unroll
            for (int c = 1; c < 16; ++c) M = fmaxf(M, mv[c]);
            float L = 0.f;
#pragma unroll
            for (int c = 0; c < 16; ++c) L += sv[c] * __expf(mv[c] - M);
            s_m[t]  = M;
            s_il[t] = 1.0f / L;
        }
#pragma unroll
        for (int it = 0; it < 2; ++it) {
            const int idx = it * 256 + t;
            const int jp  = idx >> 4;
            const int d4  = (idx & 15) * 4;
            f4 r0 = ld4(&x[(size_t)(b * 1024 + j0 + jp * 2)     * 64 + d4]);
            f4 r1 = ld4(&x[(size_t)(b * 1024 + j0 + jp * 2 + 1) * 64 + d4]);
            F4H u;
            u.h[0] = pack2(r0.x, r1.x); u.h[1] = pack2(r0.y, r1.y);
            u.h[2] = pack2(r0.z, r1.z); u.h[3] = pack2(r0.w, r1.w);
            st4((float*)&s_x[jp * 64 + d4], u.f);
        }
        __syncthreads();
#pragma unroll 2
        for (int it = 0; it < 4; ++it) {
            const int idx = it * 256 + t;
            const int rl  = idx >> 3;          // 0..127
            const int j8  = (idx & 7) * 8;
            F4H u;
            u.f = ld4((const float*)&l16[(size_t)(gr + rl) * 1024 + j0 + j8]);
            const float m  = s_m[rl];
            const float il = s_il[rl];
            float p[8];
#pragma unroll
            for (int k = 0; k < 4; ++k) {
                p[2 * k]     = __expf((float)u.h[k].x - m) * il;
                p[2 * k + 1] = __expf((float)u.h[k].y - m) * il;
            }
            float* ap = &attn[(size_t)(gr + rl) * 1024 + j0 + j8];
            st4(ap,     make_float4(p[0], p[1], p[2], p[3]));
            st4(ap + 4, make_float4(p[4], p[5], p[6], p[7]));
            const int jp0 = (idx & 7) * 4;
#pragma unroll
            for (int k = 0; k < 4; ++k)
                s_p[(jp0 + k) * PS + rl] = pack2(p[2 * k], p[2 * k + 1]);
        }
        __syncthreads();
        const int tx = t & 15;  // d quad
        const int ty = t >> 4;  // i oct (0..15)
        float acc[8][4];
#pragma unroll
        for (int ii = 0; ii < 8; ++ii)
#pragma unroll
            for (int dd = 0; dd < 4; ++dd) acc[ii][dd] = 0.f;
#pragma unroll 4
        for (int jp = 0; jp < 32; ++jp) {
            F4H a0, a1, xv;
            a0.f = ld4((const float*)&s_p[jp * PS + ty * 8]);
            a1.f = ld4((const float*)&s_p[jp * PS + ty * 8 + 4]);
            xv.f = ld4((const float*)&s_x[jp * 64 + tx * 4]);
            h2v aa[8] = {a0.h[0], a0.h[1], a0.h[2], a0.h[3],
                         a1.h[0], a1.h[1], a1.h[2], a1.h[3]};
#pragma unroll
            for (int ii = 0; ii < 8; ++ii)
#pragma unroll
                for (int dd = 0; dd < 4; ++dd)
                    acc[ii][dd] = fdot2f(aa[ii], xv.h[dd], acc[ii][dd]);
        }
#pragma unroll
        for (int ii = 0; ii < 8; ++ii) {
            f4 o = make_float4(acc[ii][0], acc[ii][1], acc[ii][2], acc[ii][3]);
            st4(&part[(size_t)(ks * 4096 + gr + ty * 8 + ii) * 64 + tx * 4], o);
        }
    }
    grid.sync();

    // ======== Phase E: updated = sum of 16 partials -> d_out[0:262144] ========
    {
        const int idx = bid * 256 + t;     // f4 index, 65536 active
        if (idx < 65536) {
            f4 a = ld4(&part[(size_t)idx * 4]);
#pragma unroll
            for (int ks = 1; ks < 16; ++ks) {
                f4 v = ld4(&part[(size_t)ks * 262144 + idx * 4]);
                a.x += v.x; a.y += v.y; a.z += v.z; a.w += v.w;
            }
            st4(&out[(size_t)idx * 4], a);
        }
    }
}

extern "C" void kernel_launch(void* const* d_in, const int* in_sizes, int n_in,
                              void* d_out, int out_size, void* d_ws, size_t ws_size,
                              hipStream_t stream) {
    const float* x  = (const float*)d_in[0];
    const float* W1 = (const float*)d_in[1];
    const float* b1 = (const float*)d_in[2];
    const float* W2 = (const float*)d_in[3];
    // d_in[4] = b2: softmax shift-invariance -> unused.
    float* out = (float*)d_out;
    float* ws  = (float*)d_ws;
    h2v*      hiP  = (h2v*)(ws + WS_HIP);
    h2v*      hjP  = (h2v*)(ws + WS_HJP);
    _Float16* l16  = (_Float16*)(ws + WS_L16);
    float*    smax = ws + WS_SMAX;
    float*    ssum = ws + WS_SSUM;
    float*    part = ws + WS_PART;
    float*    attn = out + ATTN_OFF;

    void* args[] = {(void*)&x, (void*)&W1, (void*)&b1, (void*)&W2,
                    (void*)&hiP, (void*)&hjP, (void*)&l16, (void*)&smax,
                    (void*)&ssum, (void*)&part, (void*)&attn, (void*)&out};
    hipLaunchCooperativeKernel((const void*)fused, dim3(512), dim3(256),
                               args, 0, stream);
}

// Round 6
// 107.174 us; speedup vs baseline: 2.6930x; 2.6930x over previous
//
#include <hip/hip_runtime.h>

// Problem: B=4, N=1024, H=64.
// d_out: [0..262143] updated (b,i,d) fp32 ; [262144..4456447] attn (b,i,j) fp32
#define ATTN_OFF 262144

// ws float-slot offsets (1 slot = 4B):
#define WS_HIP  0          // hiP h2v-packed [b][32 hp][1024 i]        131072 slots
#define WS_HJP  131072     // hjP same                                  131072
#define WS_L16  262144     // logits fp16 [b][1024][1024]              2097152
#define WS_SMAX 2359296    // smax [16 chunk][4096 row] fp32             65536
#define WS_SSUM 2424832    // ssum [16][4096] fp32                       65536

typedef float4 f4;
typedef _Float16 h2v __attribute__((ext_vector_type(2)));

union F4H { f4 f; h2v h[4]; };
union F2H { float2 f; h2v h[2]; };

__device__ __forceinline__ f4 ld4(const float* p) { return *reinterpret_cast<const f4*>(p); }
__device__ __forceinline__ void st4(float* p, f4 v) { *reinterpret_cast<f4*>(p) = v; }
__device__ __forceinline__ float fdot2f(h2v a, h2v b, float c) {
    return __builtin_amdgcn_fdot2(a, b, c, false);   // v_dot2_f32_f16
}
__device__ __forceinline__ h2v pack2(float a, float b) {
    h2v r; r.x = (_Float16)a; r.y = (_Float16)b; return r;
}

// ---------------- Kernel A: hi' = x@W1a^T + b1 ; hj = x@W1b^T. fp16 h-pair packed out.
__global__ __launch_bounds__(256, 4)
void ka_proj(const float* __restrict__ x, const float* __restrict__ W1,
             const float* __restrict__ b1,
             h2v* __restrict__ hiP, h2v* __restrict__ hjP) {
    __shared__ float xT[64 * 68];   // xT[d][i]
    __shared__ float w1T[64 * 68];  // w1T[d][c] = W1[c][z*64+d]
    const int t  = threadIdx.x;
    const int i0 = blockIdx.x * 64;
    const int b  = blockIdx.y;
    const int z  = blockIdx.z;
    const int lo = t & 15;
    const int dq = t >> 4;
#pragma unroll
    for (int p = 0; p < 4; ++p) {
        const int il = p * 16 + lo;
        f4 v = ld4(&x[(size_t)(b * 1024 + i0 + il) * 64 + dq * 4]);
        xT[(dq * 4 + 0) * 68 + il] = v.x;
        xT[(dq * 4 + 1) * 68 + il] = v.y;
        xT[(dq * 4 + 2) * 68 + il] = v.z;
        xT[(dq * 4 + 3) * 68 + il] = v.w;
        f4 w = ld4(&W1[(size_t)il * 128 + z * 64 + dq * 4]);
        w1T[(dq * 4 + 0) * 68 + il] = w.x;
        w1T[(dq * 4 + 1) * 68 + il] = w.y;
        w1T[(dq * 4 + 2) * 68 + il] = w.z;
        w1T[(dq * 4 + 3) * 68 + il] = w.w;
    }
    __syncthreads();
    const int tx = t & 15;   // channel quad
    const int ty = t >> 4;   // i quad
    float acc[4][4];
    if (z == 0) {
        f4 bv = ld4(&b1[tx * 4]);
        float ba[4] = {bv.x, bv.y, bv.z, bv.w};
#pragma unroll
        for (int ii = 0; ii < 4; ++ii)
#pragma unroll
            for (int cc = 0; cc < 4; ++cc) acc[ii][cc] = ba[cc];
    } else {
#pragma unroll
        for (int ii = 0; ii < 4; ++ii)
#pragma unroll
            for (int cc = 0; cc < 4; ++cc) acc[ii][cc] = 0.f;
    }
#pragma unroll 8
    for (int d = 0; d < 64; ++d) {
        f4 xv = ld4(&xT[d * 68 + ty * 4]);
        f4 wv = ld4(&w1T[d * 68 + tx * 4]);
        float xa[4] = {xv.x, xv.y, xv.z, xv.w};
        float wa[4] = {wv.x, wv.y, wv.z, wv.w};
#pragma unroll
        for (int ii = 0; ii < 4; ++ii)
#pragma unroll
            for (int cc = 0; cc < 4; ++cc)
                acc[ii][cc] = fmaf(xa[ii], wa[cc], acc[ii][cc]);
    }
    h2v* outp = z ? hjP : hiP;
#pragma unroll
    for (int p = 0; p < 2; ++p) {
        F4H u;
#pragma unroll
        for (int ii = 0; ii < 4; ++ii)
            u.h[ii] = pack2(acc[ii][p * 2 + 0], acc[ii][p * 2 + 1]);
        st4((float*)&outp[(size_t)(b * 32 + tx * 2 + p) * 1024 + i0 + ty * 4], u.f);
    }
}

// ---------------- Kernel B: logits (fp16) + per-chunk softmax stats. dot2 inner loop.
__global__ __launch_bounds__(256, 4)
void kb_logits(const h2v* __restrict__ hiP, const h2v* __restrict__ hjP,
               const float* __restrict__ W2, _Float16* __restrict__ l16,
               float* __restrict__ smax, float* __restrict__ ssum) {
    __shared__ __align__(16) h2v s_hi[32 * 128];  // [hp][i]
    __shared__ __align__(16) h2v s_hj[32 * 64];   // [hp][j]
    __shared__ h2v s_w2[32];
    const int t  = threadIdx.x;
    const int jT = blockIdx.x;
    const int iT = blockIdx.y;
    const int b  = blockIdx.z;
#pragma unroll
    for (int p = 0; p < 4; ++p) {
        const int idx = p * 256 + t;
        const int hp  = idx >> 5;
        const int c4  = (idx & 31) * 4;
        st4((float*)&s_hi[hp * 128 + c4],
            ld4((const float*)&hiP[(size_t)(b * 32 + hp) * 1024 + iT * 128 + c4]));
    }
#pragma unroll
    for (int p = 0; p < 2; ++p) {
        const int idx = p * 256 + t;
        const int hp  = idx >> 4;
        const int c4  = (idx & 15) * 4;
        st4((float*)&s_hj[hp * 64 + c4],
            ld4((const float*)&hjP[(size_t)(b * 32 + hp) * 1024 + jT * 64 + c4]));
    }
    if (t < 16) {
        f4 w = ld4(&W2[t * 4]);
        s_w2[t * 2]     = pack2(w.x, w.y);
        s_w2[t * 2 + 1] = pack2(w.z, w.w);
    }
    __syncthreads();
    const int tx = t & 15;  // j quad
    const int ty = t >> 4;  // i oct
    float acc[8][4];
#pragma unroll
    for (int ii = 0; ii < 8; ++ii)
#pragma unroll
        for (int jj = 0; jj < 4; ++jj) acc[ii][jj] = 0.f;
    const h2v z2 = (h2v)0;
#pragma unroll 4
    for (int hp = 0; hp < 32; ++hp) {
        F4H a0, a1, bb;
        a0.f = ld4((const float*)&s_hi[hp * 128 + ty * 8]);
        a1.f = ld4((const float*)&s_hi[hp * 128 + ty * 8 + 4]);
        bb.f = ld4((const float*)&s_hj[hp * 64 + tx * 4]);
        const h2v w2p = s_w2[hp];
#pragma unroll
        for (int ii = 0; ii < 8; ++ii) {
            const h2v av = (ii < 4) ? a0.h[ii] : a1.h[ii - 4];
#pragma unroll
            for (int jj = 0; jj < 4; ++jj) {
                h2v r = __builtin_elementwise_max(av + bb.h[jj], z2);
                acc[ii][jj] = fdot2f(r, w2p, acc[ii][jj]);
            }
        }
    }
#pragma unroll
    for (int ii = 0; ii < 8; ++ii) {
        const int row = b * 1024 + iT * 128 + ty * 8 + ii;
        F2H uo;
        uo.h[0] = pack2(acc[ii][0], acc[ii][1]);
        uo.h[1] = pack2(acc[ii][2], acc[ii][3]);
        *reinterpret_cast<float2*>(&l16[(size_t)row * 1024 + jT * 64 + tx * 4]) = uo.f;
        float m = fmaxf(fmaxf(acc[ii][0], acc[ii][1]), fmaxf(acc[ii][2], acc[ii][3]));
#pragma unroll
        for (int d = 1; d < 16; d <<= 1) m = fmaxf(m, __shfl_xor(m, d));
        float s = __expf(acc[ii][0] - m) + __expf(acc[ii][1] - m) +
                  __expf(acc[ii][2] - m) + __expf(acc[ii][3] - m);
#pragma unroll
        for (int d = 1; d < 16; d <<= 1) s += __shfl_xor(s, d);
        if (tx == 0) {
            smax[jT * 4096 + row] = m;
            ssum[jT * 4096 + row] = s;
        }
    }
}

// ---------------- Kernel D: stats-merge + normalize + attn write + AV + in-block K-reduce.
// grid (64 iT, 4 b) = 256 blocks x 512 thr (8 waves). Block owns 16 rows x ALL 1024 j:
// K-split across the 8 waves (each wave 16 jp per 256-j chunk), cross-wave LDS reduce at end.
// No partials buffer, no ke kernel, no atomics.
__global__ __launch_bounds__(512, 1)
void kd_av(const _Float16* __restrict__ l16, const float* __restrict__ smax,
           const float* __restrict__ ssum, const float* __restrict__ x,
           float* __restrict__ attn, float* __restrict__ out) {
    __shared__ __align__(16) h2v s_x[128 * 64];   // [jp][d] (x[2jp,d],x[2jp+1,d]) 32KB
    __shared__ __align__(16) h2v s_p[128 * 16];   // [jp][r] (a[r,2jp],a[r,2jp+1])  8KB
    __shared__ float s_m[16];
    __shared__ float s_il[16];
    const int t  = threadIdx.x;
    const int iT = blockIdx.x;            // 0..63 (16 rows each)
    const int b  = blockIdx.y;
    const int gr = b * 1024 + iT * 16;    // global row base
    // merge 16 chunk stats: 256 threads, 16 lanes per row, shuffle-reduce
    if (t < 256) {
        const int r = t >> 4, c = t & 15;
        const float m = smax[c * 4096 + gr + r];
        const float s = ssum[c * 4096 + gr + r];
        float M = m;
#pragma unroll
        for (int d = 1; d < 16; d <<= 1) M = fmaxf(M, __shfl_xor(M, d));
        float L = s * __expf(m - M);
#pragma unroll
        for (int d = 1; d < 16; d <<= 1) L += __shfl_xor(L, d);
        if (c == 0) { s_m[r] = M; s_il[r] = 1.0f / L; }
    }
    const int lane = t & 63;
    const int w    = t >> 6;    // wave 0..7
    const int rq   = lane >> 4; // row quad 0..3
    const int d4   = lane & 15; // d quad 0..15
    float acc[4][4];
#pragma unroll
    for (int ri = 0; ri < 4; ++ri)
#pragma unroll
        for (int di = 0; di < 4; ++di) acc[ri][di] = 0.f;
    for (int c = 0; c < 4; ++c) {
        const int j0 = c * 256;
        __syncthreads();   // protect s_x/s_p from previous chunk's readers
        // stage x chunk as j-pair-packed fp16: 128 jp x 64 d
#pragma unroll
        for (int it = 0; it < 4; ++it) {
            const int idx = it * 512 + t;
            const int jp  = idx >> 4;
            const int dd  = (idx & 15) * 4;
            f4 r0 = ld4(&x[(size_t)(b * 1024 + j0 + jp * 2)     * 64 + dd]);
            f4 r1 = ld4(&x[(size_t)(b * 1024 + j0 + jp * 2 + 1) * 64 + dd]);
            F4H u;
            u.h[0] = pack2(r0.x, r1.x); u.h[1] = pack2(r0.y, r1.y);
            u.h[2] = pack2(r0.z, r1.z); u.h[3] = pack2(r0.w, r1.w);
            st4((float*)&s_x[jp * 64 + dd], u.f);
        }
        // normalize logits -> attn (fp32, coalesced) + s_p scatter (4-way max)
        {
            const int rl = t & 15;           // row 0..15
            const int j8 = (t >> 4) * 8;     // 32 j-octs
            F4H u;
            u.f = ld4((const float*)&l16[(size_t)(gr + rl) * 1024 + j0 + j8]);
            const float m  = s_m[rl];
            const float il = s_il[rl];
            float p[8];
#pragma unroll
            for (int k = 0; k < 4; ++k) {
                p[2 * k]     = __expf((float)u.h[k].x - m) * il;
                p[2 * k + 1] = __expf((float)u.h[k].y - m) * il;
            }
            float* ap = &attn[(size_t)(gr + rl) * 1024 + j0 + j8];
            st4(ap,     make_float4(p[0], p[1], p[2], p[3]));
            st4(ap + 4, make_float4(p[4], p[5], p[6], p[7]));
            const int jp0 = (t >> 4) * 4;
#pragma unroll
            for (int k = 0; k < 4; ++k)
                s_p[(jp0 + k) * 16 + rl] = pack2(p[2 * k], p[2 * k + 1]);
        }
        __syncthreads();
        // AV: wave w accumulates its 16 jp (b128 reads, both aligned/conflict-free)
#pragma unroll 4
        for (int k = 0; k < 16; ++k) {
            const int jp = w * 16 + k;
            F4H pr, xr;
            pr.f = ld4((const float*)&s_p[jp * 16 + rq * 4]);   // 4 addrs -> bcast
            xr.f = ld4((const float*)&s_x[jp * 64 + d4 * 4]);   // 16 addrs, 4x shared
#pragma unroll
            for (int ri = 0; ri < 4; ++ri)
#pragma unroll
                for (int di = 0; di < 4; ++di)
                    acc[ri][di] = fdot2f(pr.h[ri], xr.h[di], acc[ri][di]);
        }
    }
    __syncthreads();
    // cross-wave reduce: red[w][16r x 64d] overlays s_x (8 x 1024 f32 = 32KB)
    float* red = (float*)s_x;
#pragma unroll
    for (int ri = 0; ri < 4; ++ri)
        st4(&red[w * 1024 + (rq * 4 + ri) * 64 + d4 * 4],
            make_float4(acc[ri][0], acc[ri][1], acc[ri][2], acc[ri][3]));
    __syncthreads();
    if (t < 256) {
        f4 a = ld4(&red[t * 4]);
#pragma unroll
        for (int ww = 1; ww < 8; ++ww) {
            f4 v = ld4(&red[ww * 1024 + t * 4]);
            a.x += v.x; a.y += v.y; a.z += v.z; a.w += v.w;
        }
        st4(&out[(size_t)(gr + (t >> 4)) * 64 + (t & 15) * 4], a);
    }
}

extern "C" void kernel_launch(void* const* d_in, const int* in_sizes, int n_in,
                              void* d_out, int out_size, void* d_ws, size_t ws_size,
                              hipStream_t stream) {
    const float* x  = (const float*)d_in[0];
    const float* W1 = (const float*)d_in[1];
    const float* b1 = (const float*)d_in[2];
    const float* W2 = (const float*)d_in[3];
    // d_in[4] = b2: softmax shift-invariance -> unused.
    float* out = (float*)d_out;
    float* ws  = (float*)d_ws;
    h2v*      hiP  = (h2v*)(ws + WS_HIP);
    h2v*      hjP  = (h2v*)(ws + WS_HJP);
    _Float16* l16  = (_Float16*)(ws + WS_L16);
    float*    smax = ws + WS_SMAX;
    float*    ssum = ws + WS_SSUM;

    ka_proj  <<<dim3(16, 4, 2), 256, 0, stream>>>(x, W1, b1, hiP, hjP);
    kb_logits<<<dim3(16, 8, 4), 256, 0, stream>>>(hiP, hjP, W2, l16, smax, ssum);
    kd_av    <<<dim3(64, 4),    512, 0, stream>>>(l16, smax, ssum, x,
                                                  out + ATTN_OFF, out);
}